// Round 7
// baseline (44.458 us; speedup 1.0000x reference)
//
#include <hip/hip_runtime.h>

#define B_ 256
#define T_ 168
#define C_ 1024
#define H_ 24
#define TH 84   // half of T: t-split factor 2

// d_ws layout (floats): W[t*24 + k] for t in [0,168), k in [0,24); beta[k] at [168*24 + k]
// Total: 168*24 + 24 = 4056 floats = 16,224 bytes.

// One block. Thread t < 168 computes the whole column W[.][t] locally
// (W[k][t] depends only on W[j][t] for j<k -- same t, no cross-thread deps).
// Thread 168 computes beta.
__global__ __launch_bounds__(192) void ar_precompute(const float* __restrict__ w,
                                                     const float* __restrict__ bias,
                                                     float* __restrict__ ws) {
    __shared__ float lw[T_];
    const int t = threadIdx.x;
    if (t < T_) lw[t] = w[t];
    __syncthreads();
    if (t < T_) {
        float col[H_];
        #pragma unroll
        for (int k = 0; k < H_; ++k) {
            float v = (t >= k) ? lw[t - k] : 0.0f;
            #pragma unroll
            for (int j = 0; j < k; ++j)
                v += lw[T_ - k + j] * col[j];
            col[k] = v;
        }
        #pragma unroll
        for (int k = 0; k < H_; ++k)
            ws[t * H_ + k] = col[k];
    } else if (t == T_) {
        float bv = bias[0];
        float beta[H_];
        #pragma unroll
        for (int k = 0; k < H_; ++k) {
            float v = bv;
            #pragma unroll
            for (int j = 0; j < k; ++j)
                v += lw[T_ - k + j] * beta[j];
            beta[k] = v;
        }
        #pragma unroll
        for (int k = 0; k < H_; ++k)
            ws[T_ * H_ + k] = beta[k];
    }
}

// out[b,k,c] = beta[k] + sum_t W[k][t] * y[b,t,c]
// t-split for TLP: block = 256 threads = 128 c-columns x 2 t-halves.
// Grid = (C/128, B) = 2048 blocks -> 8 blocks/CU -> 32 waves/CU (occupancy cap).
// Round-7 single delta vs round-6: #pragma unroll 12 (84 = 12x7) -> ~9 loads
// in flight per wave avg (~72 KB/CU; BW-latency product ~22 KB/CU) as
// insurance against the tail of the DRAM latency distribution on the
// 4 KB-stride walk. In-flight model: R0->R3 10->20 KB = -3.35us,
// R3->R6 20->36 KB = -0.91us (diminishing past the knee, as predicted).
// h=1 deposits partials in LDS ([24][128] transposed: stride-4B across lanes,
// conflict-free); h=0 reduces, adds beta, stores.
__global__ __launch_bounds__(256, 8) void ar_main(const float* __restrict__ y,
                                                  const float* __restrict__ ws,
                                                  float* __restrict__ out) {
    __shared__ float sacc[H_ * 128];

    const int tid = threadIdx.x;
    const int c_local = tid & 127;
    // tid>>7 is uniform across each wave (lanes 0-63 share it); force scalar so
    // W addresses stay provably uniform -> s_load_dwordx4 on the scalar pipe.
    const int h = __builtin_amdgcn_readfirstlane(tid >> 7);

    const int c = blockIdx.x * 128 + c_local;
    const int b = blockIdx.y;
    const float* __restrict__ yp =
        y + (size_t)b * (size_t)(T_ * C_) + (size_t)(h * TH) * C_ + c;

    float acc[H_];
    #pragma unroll
    for (int k = 0; k < H_; ++k) acc[k] = 0.0f;

    #pragma unroll 12
    for (int tt = 0; tt < TH; ++tt) {
        const float yv = yp[(size_t)tt * C_];          // coalesced across lanes
        const float4* __restrict__ w4 = (const float4*)(ws + (h * TH + tt) * H_);
        #pragma unroll
        for (int q = 0; q < H_ / 4; ++q) {             // uniform addr -> s_load_dwordx4
            const float4 wv = w4[q];
            acc[4 * q + 0] += wv.x * yv;
            acc[4 * q + 1] += wv.y * yv;
            acc[4 * q + 2] += wv.z * yv;
            acc[4 * q + 3] += wv.w * yv;
        }
    }

    if (h == 1) {
        #pragma unroll
        for (int k = 0; k < H_; ++k)
            sacc[k * 128 + c_local] = acc[k];          // conflict-free (4B stride)
    }
    __syncthreads();
    if (h == 0) {
        const float* __restrict__ beta = ws + T_ * H_; // uniform -> s_load
        float* __restrict__ op = out + ((size_t)b * H_) * C_ + c;
        #pragma unroll
        for (int k = 0; k < H_; ++k)
            op[(size_t)k * C_] = acc[k] + sacc[k * 128 + c_local] + beta[k];
    }
}

extern "C" void kernel_launch(void* const* d_in, const int* in_sizes, int n_in,
                              void* d_out, int out_size, void* d_ws, size_t ws_size,
                              hipStream_t stream) {
    // inputs: 0=x (unused), 1=y (B,T,C), 2=w (1,168), 3=b (1,)
    const float* y    = (const float*)d_in[1];
    const float* w    = (const float*)d_in[2];
    const float* bias = (const float*)d_in[3];
    float* out = (float*)d_out;
    float* ws  = (float*)d_ws;

    ar_precompute<<<1, 192, 0, stream>>>(w, bias, ws);
    ar_main<<<dim3(C_ / 128, B_), 256, 0, stream>>>(y, ws, out);
}

// Round 8
// 39.910 us; speedup vs baseline: 1.1140x; 1.1140x over previous
//
#include <hip/hip_runtime.h>

#define B_ 256
#define T_ 168
#define C_ 1024
#define H_ 24
#define TH 84   // half of T: t-split factor 2

// d_ws layout (floats): W[t*24 + k] for t in [0,168), k in [0,24); beta[k] at [168*24 + k]
// Total: 168*24 + 24 = 4056 floats = 16,224 bytes.

// One block. Thread t < 168 computes the whole column W[.][t] locally
// (W[k][t] depends only on W[j][t] for j<k -- same t, no cross-thread deps).
// Thread 168 computes beta.
__global__ __launch_bounds__(192) void ar_precompute(const float* __restrict__ w,
                                                     const float* __restrict__ bias,
                                                     float* __restrict__ ws) {
    __shared__ float lw[T_];
    const int t = threadIdx.x;
    if (t < T_) lw[t] = w[t];
    __syncthreads();
    if (t < T_) {
        float col[H_];
        #pragma unroll
        for (int k = 0; k < H_; ++k) {
            float v = (t >= k) ? lw[t - k] : 0.0f;
            #pragma unroll
            for (int j = 0; j < k; ++j)
                v += lw[T_ - k + j] * col[j];
            col[k] = v;
        }
        #pragma unroll
        for (int k = 0; k < H_; ++k)
            ws[t * H_ + k] = col[k];
    } else if (t == T_) {
        float bv = bias[0];
        float beta[H_];
        #pragma unroll
        for (int k = 0; k < H_; ++k) {
            float v = bv;
            #pragma unroll
            for (int j = 0; j < k; ++j)
                v += lw[T_ - k + j] * beta[j];
            beta[k] = v;
        }
        #pragma unroll
        for (int k = 0; k < H_; ++k)
            ws[T_ * H_ + k] = beta[k];
    }
}

// out[b,k,c] = beta[k] + sum_t W[k][t] * y[b,t,c]
// t-split for TLP: block = 256 threads = 128 c-columns x 2 t-halves.
// Grid = (C/128, B) = 2048 blocks -> 8 blocks/CU -> 32 waves/CU (occupancy cap).
// unroll 6 (84 = 6x14): ~4.5 loads in flight per wave avg (~36 KB/CU vs the
// ~22 KB/CU BW-latency product). Unroll sweep complete and unimodal:
// 4 -> 40.85us, 6 -> 39.94us, 12 -> 44.46us (VGPR pressure + issue burst).
// NO nontemporal (R4: regression). Fusion attempts (R2 LDS-W, R5 rotating
// window) both lost to the scalar-path two-kernel structure.
// h=1 deposits partials in LDS ([24][128] transposed: stride-4B across lanes,
// conflict-free); h=0 reduces, adds beta, stores.
__global__ __launch_bounds__(256, 8) void ar_main(const float* __restrict__ y,
                                                  const float* __restrict__ ws,
                                                  float* __restrict__ out) {
    __shared__ float sacc[H_ * 128];

    const int tid = threadIdx.x;
    const int c_local = tid & 127;
    // tid>>7 is uniform across each wave (lanes 0-63 share it); force scalar so
    // W addresses stay provably uniform -> s_load_dwordx4 on the scalar pipe.
    const int h = __builtin_amdgcn_readfirstlane(tid >> 7);

    const int c = blockIdx.x * 128 + c_local;
    const int b = blockIdx.y;
    const float* __restrict__ yp =
        y + (size_t)b * (size_t)(T_ * C_) + (size_t)(h * TH) * C_ + c;

    float acc[H_];
    #pragma unroll
    for (int k = 0; k < H_; ++k) acc[k] = 0.0f;

    #pragma unroll 6
    for (int tt = 0; tt < TH; ++tt) {
        const float yv = yp[(size_t)tt * C_];          // coalesced across lanes
        const float4* __restrict__ w4 = (const float4*)(ws + (h * TH + tt) * H_);
        #pragma unroll
        for (int q = 0; q < H_ / 4; ++q) {             // uniform addr -> s_load_dwordx4
            const float4 wv = w4[q];
            acc[4 * q + 0] += wv.x * yv;
            acc[4 * q + 1] += wv.y * yv;
            acc[4 * q + 2] += wv.z * yv;
            acc[4 * q + 3] += wv.w * yv;
        }
    }

    if (h == 1) {
        #pragma unroll
        for (int k = 0; k < H_; ++k)
            sacc[k * 128 + c_local] = acc[k];          // conflict-free (4B stride)
    }
    __syncthreads();
    if (h == 0) {
        const float* __restrict__ beta = ws + T_ * H_; // uniform -> s_load
        float* __restrict__ op = out + ((size_t)b * H_) * C_ + c;
        #pragma unroll
        for (int k = 0; k < H_; ++k)
            op[(size_t)k * C_] = acc[k] + sacc[k * 128 + c_local] + beta[k];
    }
}

extern "C" void kernel_launch(void* const* d_in, const int* in_sizes, int n_in,
                              void* d_out, int out_size, void* d_ws, size_t ws_size,
                              hipStream_t stream) {
    // inputs: 0=x (unused), 1=y (B,T,C), 2=w (1,168), 3=b (1,)
    const float* y    = (const float*)d_in[1];
    const float* w    = (const float*)d_in[2];
    const float* bias = (const float*)d_in[3];
    float* out = (float*)d_out;
    float* ws  = (float*)d_ws;

    ar_precompute<<<1, 192, 0, stream>>>(w, bias, ws);
    ar_main<<<dim3(C_ / 128, B_), 256, 0, stream>>>(y, ws, out);
}